// Round 2
// baseline (915.813 us; speedup 1.0000x reference)
//
#include <hip/hip_runtime.h>
#include <cstdint>
#include <cstddef>

#define M_DIM 8192
#define N_DIM 4096
#define K_DIM 4096

#define BM 128
#define BN 128
#define BK 128   // bytes of K per tile (i8 elements)

typedef int int32x4 __attribute__((ext_vector_type(4)));

// ws layout (as int32*):
//   [0] = flagA (1 -> qinput stored as packed int8, 0 -> widened int32)
//   [1] = flagB (same for qweight)
//   [16 .. 16+N)        qb      (shifted bias)
//   [16+N .. 16+2N)     int_scale
//   [16+2N .. 16+3N)    frac_bits

typedef __attribute__((address_space(1))) const void* gas_cptr;
typedef __attribute__((address_space(3))) void* las_ptr;

__device__ __forceinline__ void async_copy16(const void* g, void* l) {
    __builtin_amdgcn_global_load_lds((gas_cptr)g, (las_ptr)l, 16, 0, 0);
}

__device__ __forceinline__ int32x4 pack16(const int* p) {
    const int32x4* v = (const int32x4*)p;
    int32x4 w0 = v[0], w1 = v[1], w2 = v[2], w3 = v[3];
    int32x4 r;
    r.x = (w0.x & 0xFF) | ((w0.y & 0xFF) << 8) | ((w0.z & 0xFF) << 16) | (w0.w << 24);
    r.y = (w1.x & 0xFF) | ((w1.y & 0xFF) << 8) | ((w1.z & 0xFF) << 16) | (w1.w << 24);
    r.z = (w2.x & 0xFF) | ((w2.y & 0xFF) << 8) | ((w2.z & 0xFF) << 16) | (w2.w << 24);
    r.w = (w3.x & 0xFF) | ((w3.y & 0xFF) << 8) | ((w3.z & 0xFF) << 16) | (w3.w << 24);
    return r;
}

__global__ void ql_detect_kernel(const int* a, const int* b, int* ws) {
    int t = threadIdx.x;  // 64 threads
    int fa = 0, fb = 0;
    for (int i = t; i < 4096; i += 64) {
        int va = a[i]; if (va > 127 || va < -128) fa = 1;
        int vb = b[i]; if (vb > 127 || vb < -128) fb = 1;
    }
    unsigned long long ba = __ballot(fa);
    unsigned long long bb = __ballot(fb);
    if (t == 0) { ws[0] = ba ? 1 : 0; ws[1] = bb ? 1 : 0; }
}

// One wave per output channel n: rowsum of qweight + requant params.
__global__ void ql_prep_kernel(const void* wptr, const int* qbias,
                               const float* wscale, int* ws) {
    const int lane = threadIdx.x & 63;
    const int wid  = threadIdx.x >> 6;
    const int n = blockIdx.x * 4 + wid;
    const int b8 = __builtin_amdgcn_readfirstlane(ws[1]);

    int s = 0;
    if (b8) {
        const int32x4* row = (const int32x4*)((const int8_t*)wptr + (size_t)n * K_DIM);
        for (int c = lane; c < K_DIM / 16; c += 64) {
            int32x4 v = row[c];
#pragma unroll
            for (int j = 0; j < 4; ++j) {
                int w = (j == 0) ? v.x : (j == 1) ? v.y : (j == 2) ? v.z : v.w;
                s += (int)(int8_t)(w) + (int)(int8_t)(w >> 8)
                   + (int)(int8_t)(w >> 16) + (int)(int8_t)(w >> 24);
            }
        }
    } else {
        const int32x4* row = (const int32x4*)((const int*)wptr + (size_t)n * K_DIM);
        for (int c = lane; c < K_DIM / 4; c += 64) {
            int32x4 v = row[c];
            s += v.x + v.y + v.z + v.w;
        }
    }
#pragma unroll
    for (int off = 32; off > 0; off >>= 1) s += __shfl_down(s, off, 64);

    if (lane == 0) {
        // shifted_qbias = qbias - rowsum * Zin, Zin = -3
        ws[16 + n] = qbias[n] + 3 * s;
        float folded = (0.05f * wscale[n]) / 0.1f;          // in (0,1)
        float fbf = 7.0f - ceilf(log2f(folded));            // float, exact integer
        int fbits = (int)fbf;
        int isc = (int)rintf(folded * exp2f((float)fbits)); // nearest-even == np.round
        ws[16 + N_DIM + n] = isc;
        ws[16 + 2 * N_DIM + n] = fbits;
    }
}

__global__ __launch_bounds__(256)
void ql_gemm_kernel(const void* aptr, const void* bptr, const int* ws, int* out) {
    __shared__ int32x4 Als[BM * BK / 16];   // 16 KB
    __shared__ int32x4 Bls[BN * BK / 16];   // 16 KB

    const int a8 = __builtin_amdgcn_readfirstlane(ws[0]);
    const int b8 = __builtin_amdgcn_readfirstlane(ws[1]);

    const int t    = threadIdx.x;
    const int lane = t & 63;
    const int wid  = t >> 6;
    const int bn = blockIdx.x;      // N/128 = 32
    const int bm = blockIdx.y;      // M/128 = 64

    const int wm = (wid >> 1) * 64;
    const int wn = (wid & 1) * 64;
    const int qm = lane & 15;       // row (A) / col-channel (B) within 16x16
    const int qh = lane >> 4;       // 0..3, selects k-subchunk

    int32x4 acc[4][4] = {};

    for (int kt = 0; kt < K_DIM / BK; ++kt) {
        __syncthreads();
        const int k0 = kt * BK;
#pragma unroll
        for (int r = 0; r < 4; ++r) {
            const int c   = r * 256 + t;       // chunk id 0..1023 (16B chunks)
            const int row = c >> 3;            // 8 chunks per 128B row
            const int kc  = (c & 7) * 16;      // byte offset in row
            const size_t offA = (size_t)(bm * BM + row) * K_DIM + k0 + kc;
            const size_t offB = (size_t)(bn * BN + row) * K_DIM + k0 + kc;
            if (a8) {
                async_copy16((const int8_t*)aptr + offA, &Als[c]);
            } else {
                Als[c] = pack16((const int*)aptr + offA);
            }
            if (b8) {
                async_copy16((const int8_t*)bptr + offB, &Bls[c]);
            } else {
                Bls[c] = pack16((const int*)bptr + offB);
            }
        }
        __syncthreads();

#pragma unroll
        for (int s = 0; s < 2; ++s) {
            const int koff = s * 64 + qh * 16;  // byte offset within BK row
            int32x4 af[4], bf[4];
#pragma unroll
            for (int i = 0; i < 4; ++i) {
                af[i] = Als[((wm + i * 16 + qm) * BK + koff) >> 4];
                bf[i] = Bls[((wn + i * 16 + qm) * BK + koff) >> 4];
            }
#pragma unroll
            for (int i = 0; i < 4; ++i)
#pragma unroll
                for (int j = 0; j < 4; ++j)
                    acc[i][j] = __builtin_amdgcn_mfma_i32_16x16x64_i8(
                        af[i], bf[j], acc[i][j], 0, 0, 0);
        }
    }

    // epilogue: requantize + store as int32
    const int* qb  = ws + 16;
    const int* isc = ws + 16 + N_DIM;
    const int* fbt = ws + 16 + 2 * N_DIM;
#pragma unroll
    for (int j = 0; j < 4; ++j) {
        const int n_g = bn * BN + wn + j * 16 + qm;
        const int b0 = qb[n_g];
        const int s0 = isc[n_g];
        const int f0 = fbt[n_g];
#pragma unroll
        for (int i = 0; i < 4; ++i) {
            const int m_base = bm * BM + wm + i * 16 + qh * 4;
#pragma unroll
            for (int r = 0; r < 4; ++r) {
                int v = ((r == 0) ? acc[i][j].x : (r == 1) ? acc[i][j].y
                        : (r == 2) ? acc[i][j].z : acc[i][j].w) + b0;
                long long p = (long long)v * (long long)s0;
                int o = (int)(p >> f0) - 5;           // + OUTPUT_ZERO_POINT (-5)
                o = o < -128 ? -128 : (o > 127 ? 127 : o);
                out[(size_t)(m_base + r) * N_DIM + n_g] = o;
            }
        }
    }
}

extern "C" void kernel_launch(void* const* d_in, const int* in_sizes, int n_in,
                              void* d_out, int out_size, void* d_ws, size_t ws_size,
                              hipStream_t stream) {
    const void* qin    = d_in[0];
    const void* qwt    = d_in[1];
    const int* qbias   = (const int*)d_in[2];
    const float* wscal = (const float*)d_in[3];
    int* ws  = (int*)d_ws;
    int* out = (int*)d_out;

    hipLaunchKernelGGL(ql_detect_kernel, dim3(1), dim3(64), 0, stream,
                       (const int*)qin, (const int*)qwt, ws);
    hipLaunchKernelGGL(ql_prep_kernel, dim3(N_DIM / 4), dim3(256), 0, stream,
                       qwt, qbias, wscal, ws);
    hipLaunchKernelGGL(ql_gemm_kernel, dim3(N_DIM / BN, M_DIM / BM), dim3(256), 0, stream,
                       qin, qwt, ws, out);
}

// Round 3
// 443.894 us; speedup vs baseline: 2.0631x; 2.0631x over previous
//
#include <hip/hip_runtime.h>
#include <cstdint>
#include <cstddef>

#define M_DIM 8192
#define N_DIM 4096
#define K_DIM 4096

#define BM 128
#define BN 128
#define BK 128   // i8 elements of K per tile

typedef int int32x4 __attribute__((ext_vector_type(4)));

// ws layout:
//   int32 header (64 KB):
//     [0] = flagA (1 -> stored packed int8, 0 -> widened int32)
//     [1] = flagB
//     [16 .. 16+N)      qb (shifted bias)
//     [16+N .. 16+2N)   int_scale
//     [16+2N .. 16+3N)  frac_bits
//   byte 65536:           A8  (M*K int8)
//   byte 65536 + M*K:     W8  (N*K int8)

typedef __attribute__((address_space(1))) const void* gas_cptr;
typedef __attribute__((address_space(3))) void* las_ptr;

__device__ __forceinline__ void async_copy16(const void* g, void* l) {
    __builtin_amdgcn_global_load_lds((gas_cptr)g, (las_ptr)l, 16, 0, 0);
}

__device__ __forceinline__ int32x4 pack16(const int* p) {
    const int32x4* v = (const int32x4*)p;
    int32x4 w0 = v[0], w1 = v[1], w2 = v[2], w3 = v[3];
    int32x4 r;
    r.x = (w0.x & 0xFF) | ((w0.y & 0xFF) << 8) | ((w0.z & 0xFF) << 16) | (w0.w << 24);
    r.y = (w1.x & 0xFF) | ((w1.y & 0xFF) << 8) | ((w1.z & 0xFF) << 16) | (w1.w << 24);
    r.z = (w2.x & 0xFF) | ((w2.y & 0xFF) << 8) | ((w2.z & 0xFF) << 16) | (w2.w << 24);
    r.w = (w3.x & 0xFF) | ((w3.y & 0xFF) << 8) | ((w3.z & 0xFF) << 16) | (w3.w << 24);
    return r;
}

__global__ void ql_detect_kernel(const int* a, const int* b, int* ws) {
    int t = threadIdx.x;  // 64 threads
    int fa = 0, fb = 0;
    for (int i = t; i < 4096; i += 64) {
        int va = a[i]; if (va > 127 || va < -128) fa = 1;
        int vb = b[i]; if (vb > 127 || vb < -128) fb = 1;
    }
    unsigned long long ba = __ballot(fa);
    unsigned long long bb = __ballot(fb);
    // flag = 1 means "stored as packed int8"
    if (t == 0) { ws[0] = ba ? 1 : 0; ws[1] = bb ? 1 : 0; }
}

// int32 -> int8 repack (or passthrough copy if already int8). One 16B chunk/thread.
__global__ __launch_bounds__(256)
void ql_pack_kernel(const void* src, int8_t* dst, const int* ws, int flag_idx, long n16) {
    const int f8 = __builtin_amdgcn_readfirstlane(ws[flag_idx]);
    long c = (long)blockIdx.x * 256 + threadIdx.x;
    if (c >= n16) return;
    if (f8) {
        ((int32x4*)dst)[c] = ((const int32x4*)src)[c];
    } else {
        ((int32x4*)dst)[c] = pack16((const int*)src + c * 16);
    }
}

// One wave per output channel n: rowsum of qweight + requant params.
__global__ void ql_prep_kernel(const void* wptr, const int* qbias,
                               const float* wscale, int* ws) {
    const int lane = threadIdx.x & 63;
    const int wid  = threadIdx.x >> 6;
    const int n = blockIdx.x * 4 + wid;
    const int b8 = __builtin_amdgcn_readfirstlane(ws[1]);

    int s = 0;
    if (b8) {
        const int32x4* row = (const int32x4*)((const int8_t*)wptr + (size_t)n * K_DIM);
        for (int c = lane; c < K_DIM / 16; c += 64) {
            int32x4 v = row[c];
#pragma unroll
            for (int j = 0; j < 4; ++j) {
                int w = (j == 0) ? v.x : (j == 1) ? v.y : (j == 2) ? v.z : v.w;
                s += (int)(int8_t)(w) + (int)(int8_t)(w >> 8)
                   + (int)(int8_t)(w >> 16) + (int)(int8_t)(w >> 24);
            }
        }
    } else {
        const int32x4* row = (const int32x4*)((const int*)wptr + (size_t)n * K_DIM);
        for (int c = lane; c < K_DIM / 4; c += 64) {
            int32x4 v = row[c];
            s += v.x + v.y + v.z + v.w;
        }
    }
#pragma unroll
    for (int off = 32; off > 0; off >>= 1) s += __shfl_down(s, off, 64);

    if (lane == 0) {
        ws[16 + n] = qbias[n] + 3 * s;                       // qbias - rowsum*Zin, Zin=-3
        float folded = (0.05f * wscale[n]) / 0.1f;           // in (0,1)
        int fbits = (int)(7.0f - ceilf(log2f(folded)));
        int isc = (int)rintf(folded * exp2f((float)fbits));  // nearest-even == np.round
        ws[16 + N_DIM + n] = isc;
        ws[16 + 2 * N_DIM + n] = fbits;
    }
}

// Shared epilogue: requantize acc tile and store int32.
__device__ __forceinline__ void ql_epilogue(int32x4 acc[4][4], const int* ws,
                                            int* out, int bm, int bn,
                                            int wm, int wn, int qm, int qh) {
    const int* qb  = ws + 16;
    const int* isc = ws + 16 + N_DIM;
    const int* fbt = ws + 16 + 2 * N_DIM;
#pragma unroll
    for (int j = 0; j < 4; ++j) {
        const int n_g = bn * BN + wn + j * 16 + qm;
        const int b0 = qb[n_g];
        const int s0 = isc[n_g];
        const int f0 = fbt[n_g];
#pragma unroll
        for (int i = 0; i < 4; ++i) {
            const int m_base = bm * BM + wm + i * 16 + qh * 4;
#pragma unroll
            for (int r = 0; r < 4; ++r) {
                int v = ((r == 0) ? acc[i][j].x : (r == 1) ? acc[i][j].y
                        : (r == 2) ? acc[i][j].z : acc[i][j].w) + b0;
                long long p = (long long)v * (long long)s0;
                int o = (int)(p >> f0) - 5;            // + OUTPUT_ZERO_POINT (-5)
                o = o < -128 ? -128 : (o > 127 ? 127 : o);
                out[(size_t)(m_base + r) * N_DIM + n_g] = o;
            }
        }
    }
}

// Fast path: int8 sources (pre-packed), global_load_lds staging, XOR-swizzled LDS.
// LDS chunk (row,col) holds global k-chunk (col ^ (row&7)) of that row.
__global__ __launch_bounds__(256)
void ql_gemm_kernel(const int8_t* aptr, const int8_t* bptr, const int* ws, int* out) {
    __shared__ int32x4 Als[BM * BK / 16];   // 16 KB
    __shared__ int32x4 Bls[BN * BK / 16];   // 16 KB

    const int t    = threadIdx.x;
    const int lane = t & 63;
    const int wid  = t >> 6;
    const int bn = blockIdx.x;      // N/128 = 32
    const int bm = blockIdx.y;      // M/128 = 64

    const int wm = (wid >> 1) * 64;
    const int wn = (wid & 1) * 64;
    const int qm = lane & 15;
    const int qh = lane >> 4;

    int32x4 acc[4][4] = {};

    for (int kt = 0; kt < K_DIM / BK; ++kt) {
        __syncthreads();
        const int k0 = kt * BK;
#pragma unroll
        for (int r = 0; r < 4; ++r) {
            const int c    = r * 256 + t;                 // LDS chunk id 0..1023
            const int row  = c >> 3;
            const int colg = (c & 7) ^ (row & 7);         // inverse swizzle on source
            const size_t offA = (size_t)(bm * BM + row) * K_DIM + k0 + colg * 16;
            const size_t offB = (size_t)(bn * BN + row) * K_DIM + k0 + colg * 16;
            async_copy16(aptr + offA, &Als[c]);
            async_copy16(bptr + offB, &Bls[c]);
        }
        __syncthreads();

#pragma unroll
        for (int s = 0; s < 2; ++s) {
            const int colk = s * 4 + qh;                  // k-chunk 0..7 within BK
            int32x4 af[4], bf[4];
#pragma unroll
            for (int i = 0; i < 4; ++i) {
                const int ra = wm + i * 16 + qm;
                const int rb = wn + i * 16 + qm;
                af[i] = Als[ra * 8 + (colk ^ (ra & 7))];
                bf[i] = Bls[rb * 8 + (colk ^ (rb & 7))];
            }
#pragma unroll
            for (int i = 0; i < 4; ++i)
#pragma unroll
                for (int j = 0; j < 4; ++j)
                    acc[i][j] = __builtin_amdgcn_mfma_i32_16x16x64_i8(
                        af[i], bf[j], acc[i][j], 0, 0, 0);
        }
    }
    ql_epilogue(acc, ws, out, bm, bn, wm, wn, qm, qh);
}

// Fallback (ws too small): round-1 structure + swizzle fix, packs in-loop.
__global__ __launch_bounds__(256)
void ql_gemm_fb_kernel(const void* aptr, const void* bptr, const int* ws, int* out) {
    __shared__ int32x4 Als[BM * BK / 16];
    __shared__ int32x4 Bls[BN * BK / 16];

    const int a8 = __builtin_amdgcn_readfirstlane(ws[0]);
    const int b8 = __builtin_amdgcn_readfirstlane(ws[1]);

    const int t    = threadIdx.x;
    const int lane = t & 63;
    const int wid  = t >> 6;
    const int bn = blockIdx.x;
    const int bm = blockIdx.y;

    const int wm = (wid >> 1) * 64;
    const int wn = (wid & 1) * 64;
    const int qm = lane & 15;
    const int qh = lane >> 4;

    int32x4 acc[4][4] = {};

    for (int kt = 0; kt < K_DIM / BK; ++kt) {
        __syncthreads();
        const int k0 = kt * BK;
#pragma unroll
        for (int r = 0; r < 4; ++r) {
            const int c    = r * 256 + t;
            const int row  = c >> 3;
            const int colg = (c & 7) ^ (row & 7);
            const size_t offA = (size_t)(bm * BM + row) * K_DIM + k0 + colg * 16;
            const size_t offB = (size_t)(bn * BN + row) * K_DIM + k0 + colg * 16;
            if (a8) async_copy16((const int8_t*)aptr + offA, &Als[c]);
            else    Als[c] = pack16((const int*)aptr + offA);
            if (b8) async_copy16((const int8_t*)bptr + offB, &Bls[c]);
            else    Bls[c] = pack16((const int*)bptr + offB);
        }
        __syncthreads();

#pragma unroll
        for (int s = 0; s < 2; ++s) {
            const int colk = s * 4 + qh;
            int32x4 af[4], bf[4];
#pragma unroll
            for (int i = 0; i < 4; ++i) {
                const int ra = wm + i * 16 + qm;
                const int rb = wn + i * 16 + qm;
                af[i] = Als[ra * 8 + (colk ^ (ra & 7))];
                bf[i] = Bls[rb * 8 + (colk ^ (rb & 7))];
            }
#pragma unroll
            for (int i = 0; i < 4; ++i)
#pragma unroll
                for (int j = 0; j < 4; ++j)
                    acc[i][j] = __builtin_amdgcn_mfma_i32_16x16x64_i8(
                        af[i], bf[j], acc[i][j], 0, 0, 0);
        }
    }
    ql_epilogue(acc, ws, out, bm, bn, wm, wn, qm, qh);
}

extern "C" void kernel_launch(void* const* d_in, const int* in_sizes, int n_in,
                              void* d_out, int out_size, void* d_ws, size_t ws_size,
                              hipStream_t stream) {
    const void* qin    = d_in[0];
    const void* qwt    = d_in[1];
    const int* qbias   = (const int*)d_in[2];
    const float* wscal = (const float*)d_in[3];
    int* ws  = (int*)d_ws;
    int* out = (int*)d_out;

    hipLaunchKernelGGL(ql_detect_kernel, dim3(1), dim3(64), 0, stream,
                       (const int*)qin, (const int*)qwt, ws);
    hipLaunchKernelGGL(ql_prep_kernel, dim3(N_DIM / 4), dim3(256), 0, stream,
                       qwt, qbias, wscal, ws);

    const size_t need = 65536 + (size_t)M_DIM * K_DIM + (size_t)N_DIM * K_DIM;
    if (ws_size >= need) {
        int8_t* a8 = (int8_t*)d_ws + 65536;
        int8_t* w8 = a8 + (size_t)M_DIM * K_DIM;
        const long nA = (long)M_DIM * K_DIM / 16;
        const long nW = (long)N_DIM * K_DIM / 16;
        hipLaunchKernelGGL(ql_pack_kernel, dim3((nA + 255) / 256), dim3(256), 0, stream,
                           qin, a8, ws, 0, nA);
        hipLaunchKernelGGL(ql_pack_kernel, dim3((nW + 255) / 256), dim3(256), 0, stream,
                           qwt, w8, ws, 1, nW);
        hipLaunchKernelGGL(ql_gemm_kernel, dim3(N_DIM / BN, M_DIM / BM), dim3(256), 0, stream,
                           a8, w8, ws, out);
    } else {
        hipLaunchKernelGGL(ql_gemm_fb_kernel, dim3(N_DIM / BN, M_DIM / BM), dim3(256), 0, stream,
                           qin, qwt, ws, out);
    }
}

// Round 4
// 440.119 us; speedup vs baseline: 2.0808x; 1.0086x over previous
//
#include <hip/hip_runtime.h>
#include <cstdint>
#include <cstddef>

#define M_DIM 8192
#define N_DIM 4096
#define K_DIM 4096

#define BM 128
#define BN 128
#define BK 128   // i8 elements of K per tile

typedef int int32x4 __attribute__((ext_vector_type(4)));

// ws layout:
//   int32 header (64 KB):
//     [0] = flagA (1 -> stored packed int8, 0 -> widened int32)
//     [1] = flagB
//     [16 .. 16+N)      qb (shifted bias)
//     [16+N .. 16+2N)   int_scale
//     [16+2N .. 16+3N)  frac_bits
//   byte 65536:           A8  (M*K int8)
//   byte 65536 + M*K:     W8  (N*K int8)

typedef __attribute__((address_space(1))) const void* gas_cptr;
typedef __attribute__((address_space(3))) void* las_ptr;

__device__ __forceinline__ void async_copy16(const void* g, void* l) {
    __builtin_amdgcn_global_load_lds((gas_cptr)g, (las_ptr)l, 16, 0, 0);
}

__device__ __forceinline__ int32x4 pack16(const int* p) {
    const int32x4* v = (const int32x4*)p;
    int32x4 w0 = v[0], w1 = v[1], w2 = v[2], w3 = v[3];
    int32x4 r;
    r.x = (w0.x & 0xFF) | ((w0.y & 0xFF) << 8) | ((w0.z & 0xFF) << 16) | (w0.w << 24);
    r.y = (w1.x & 0xFF) | ((w1.y & 0xFF) << 8) | ((w1.z & 0xFF) << 16) | (w1.w << 24);
    r.z = (w2.x & 0xFF) | ((w2.y & 0xFF) << 8) | ((w2.z & 0xFF) << 16) | (w2.w << 24);
    r.w = (w3.x & 0xFF) | ((w3.y & 0xFF) << 8) | ((w3.z & 0xFF) << 16) | (w3.w << 24);
    return r;
}

__global__ void ql_detect_kernel(const int* a, const int* b, int* ws) {
    int t = threadIdx.x;  // 64 threads
    int fa = 0, fb = 0;
    for (int i = t; i < 4096; i += 64) {
        int va = a[i]; if (va > 127 || va < -128) fa = 1;
        int vb = b[i]; if (vb > 127 || vb < -128) fb = 1;
    }
    unsigned long long ba = __ballot(fa);
    unsigned long long bb = __ballot(fb);
    // flag = 1 means "stored as packed int8"
    if (t == 0) { ws[0] = ba ? 1 : 0; ws[1] = bb ? 1 : 0; }
}

// Coalesced repack: one output dword (4 int8) per lane per iteration.
// int32 path: lane reads int32x4 (16 B, unit stride across lanes), writes 4 B.
__global__ __launch_bounds__(256)
void ql_pack_kernel(const void* src, int* dst, const int* ws, int flag_idx, long ndw) {
    const int f8 = __builtin_amdgcn_readfirstlane(ws[flag_idx]);
    const long stride = (long)gridDim.x * 256;
    for (long c = (long)blockIdx.x * 256 + threadIdx.x; c < ndw; c += stride) {
        if (f8) {
            dst[c] = ((const int*)src)[c];   // already packed: plain copy
        } else {
            int32x4 v = ((const int32x4*)src)[c];
            dst[c] = (v.x & 0xFF) | ((v.y & 0xFF) << 8) | ((v.z & 0xFF) << 16) | (v.w << 24);
        }
    }
}

// Fast-path prep: rowsum + requant params from the packed W8 (16 MB read).
__global__ void ql_prep8_kernel(const int8_t* w8, const int* qbias,
                                const float* wscale, int* ws) {
    const int lane = threadIdx.x & 63;
    const int wid  = threadIdx.x >> 6;
    const int n = blockIdx.x * 4 + wid;

    const int32x4* row = (const int32x4*)(w8 + (size_t)n * K_DIM);
    int s = 0;
    for (int c = lane; c < K_DIM / 16; c += 64) {
        int32x4 v = row[c];
#pragma unroll
        for (int j = 0; j < 4; ++j) {
            int w = (j == 0) ? v.x : (j == 1) ? v.y : (j == 2) ? v.z : v.w;
            s += (int)(int8_t)(w) + (int)(int8_t)(w >> 8)
               + (int)(int8_t)(w >> 16) + (w >> 24);
        }
    }
#pragma unroll
    for (int off = 32; off > 0; off >>= 1) s += __shfl_down(s, off, 64);

    if (lane == 0) {
        ws[16 + n] = qbias[n] + 3 * s;                       // qbias - rowsum*Zin, Zin=-3
        float folded = (0.05f * wscale[n]) / 0.1f;           // in (0,1)
        int fbits = (int)(7.0f - ceilf(log2f(folded)));
        int isc = (int)rintf(folded * exp2f((float)fbits));  // nearest-even == np.round
        ws[16 + N_DIM + n] = isc;
        ws[16 + 2 * N_DIM + n] = fbits;
    }
}

// Fallback prep (ws too small): reads original W, flag-based.
__global__ void ql_prep_kernel(const void* wptr, const int* qbias,
                               const float* wscale, int* ws) {
    const int lane = threadIdx.x & 63;
    const int wid  = threadIdx.x >> 6;
    const int n = blockIdx.x * 4 + wid;
    const int b8 = __builtin_amdgcn_readfirstlane(ws[1]);

    int s = 0;
    if (b8) {
        const int32x4* row = (const int32x4*)((const int8_t*)wptr + (size_t)n * K_DIM);
        for (int c = lane; c < K_DIM / 16; c += 64) {
            int32x4 v = row[c];
#pragma unroll
            for (int j = 0; j < 4; ++j) {
                int w = (j == 0) ? v.x : (j == 1) ? v.y : (j == 2) ? v.z : v.w;
                s += (int)(int8_t)(w) + (int)(int8_t)(w >> 8)
                   + (int)(int8_t)(w >> 16) + (w >> 24);
            }
        }
    } else {
        const int32x4* row = (const int32x4*)((const int*)wptr + (size_t)n * K_DIM);
        for (int c = lane; c < K_DIM / 4; c += 64) {
            int32x4 v = row[c];
            s += v.x + v.y + v.z + v.w;
        }
    }
#pragma unroll
    for (int off = 32; off > 0; off >>= 1) s += __shfl_down(s, off, 64);

    if (lane == 0) {
        ws[16 + n] = qbias[n] + 3 * s;
        float folded = (0.05f * wscale[n]) / 0.1f;
        int fbits = (int)(7.0f - ceilf(log2f(folded)));
        int isc = (int)rintf(folded * exp2f((float)fbits));
        ws[16 + N_DIM + n] = isc;
        ws[16 + 2 * N_DIM + n] = fbits;
    }
}

// Shared epilogue: requantize acc tile and store int32.
__device__ __forceinline__ void ql_epilogue(int32x4 acc[4][4], const int* ws,
                                            int* out, int bm, int bn,
                                            int wm, int wn, int qm, int qh) {
    const int* qb  = ws + 16;
    const int* isc = ws + 16 + N_DIM;
    const int* fbt = ws + 16 + 2 * N_DIM;
#pragma unroll
    for (int j = 0; j < 4; ++j) {
        const int n_g = bn * BN + wn + j * 16 + qm;
        const int b0 = qb[n_g];
        const int s0 = isc[n_g];
        const int f0 = fbt[n_g];
#pragma unroll
        for (int i = 0; i < 4; ++i) {
            const int m_base = bm * BM + wm + i * 16 + qh * 4;
#pragma unroll
            for (int r = 0; r < 4; ++r) {
                int v = ((r == 0) ? acc[i][j].x : (r == 1) ? acc[i][j].y
                        : (r == 2) ? acc[i][j].z : acc[i][j].w) + b0;
                long long p = (long long)v * (long long)s0;
                int o = (int)(p >> f0) - 5;            // + OUTPUT_ZERO_POINT (-5)
                o = o < -128 ? -128 : (o > 127 ? 127 : o);
                out[(size_t)(m_base + r) * N_DIM + n_g] = o;
            }
        }
    }
}

// Fast path: int8 sources (pre-packed), global_load_lds staging, XOR-swizzled LDS.
// (byte-identical to round-3 verified kernel)
__global__ __launch_bounds__(256)
void ql_gemm_kernel(const int8_t* aptr, const int8_t* bptr, const int* ws, int* out) {
    __shared__ int32x4 Als[BM * BK / 16];   // 16 KB
    __shared__ int32x4 Bls[BN * BK / 16];   // 16 KB

    const int t    = threadIdx.x;
    const int lane = t & 63;
    const int wid  = t >> 6;
    const int bn = blockIdx.x;      // N/128 = 32
    const int bm = blockIdx.y;      // M/128 = 64

    const int wm = (wid >> 1) * 64;
    const int wn = (wid & 1) * 64;
    const int qm = lane & 15;
    const int qh = lane >> 4;

    int32x4 acc[4][4] = {};

    for (int kt = 0; kt < K_DIM / BK; ++kt) {
        __syncthreads();
        const int k0 = kt * BK;
#pragma unroll
        for (int r = 0; r < 4; ++r) {
            const int c    = r * 256 + t;                 // LDS chunk id 0..1023
            const int row  = c >> 3;
            const int colg = (c & 7) ^ (row & 7);         // inverse swizzle on source
            const size_t offA = (size_t)(bm * BM + row) * K_DIM + k0 + colg * 16;
            const size_t offB = (size_t)(bn * BN + row) * K_DIM + k0 + colg * 16;
            async_copy16(aptr + offA, &Als[c]);
            async_copy16(bptr + offB, &Bls[c]);
        }
        __syncthreads();

#pragma unroll
        for (int s = 0; s < 2; ++s) {
            const int colk = s * 4 + qh;                  // k-chunk 0..7 within BK
            int32x4 af[4], bf[4];
#pragma unroll
            for (int i = 0; i < 4; ++i) {
                const int ra = wm + i * 16 + qm;
                const int rb = wn + i * 16 + qm;
                af[i] = Als[ra * 8 + (colk ^ (ra & 7))];
                bf[i] = Bls[rb * 8 + (colk ^ (rb & 7))];
            }
#pragma unroll
            for (int i = 0; i < 4; ++i)
#pragma unroll
                for (int j = 0; j < 4; ++j)
                    acc[i][j] = __builtin_amdgcn_mfma_i32_16x16x64_i8(
                        af[i], bf[j], acc[i][j], 0, 0, 0);
        }
    }
    ql_epilogue(acc, ws, out, bm, bn, wm, wn, qm, qh);
}

// Fallback (ws too small): packs in-loop.
__global__ __launch_bounds__(256)
void ql_gemm_fb_kernel(const void* aptr, const void* bptr, const int* ws, int* out) {
    __shared__ int32x4 Als[BM * BK / 16];
    __shared__ int32x4 Bls[BN * BK / 16];

    const int a8 = __builtin_amdgcn_readfirstlane(ws[0]);
    const int b8 = __builtin_amdgcn_readfirstlane(ws[1]);

    const int t    = threadIdx.x;
    const int lane = t & 63;
    const int wid  = t >> 6;
    const int bn = blockIdx.x;
    const int bm = blockIdx.y;

    const int wm = (wid >> 1) * 64;
    const int wn = (wid & 1) * 64;
    const int qm = lane & 15;
    const int qh = lane >> 4;

    int32x4 acc[4][4] = {};

    for (int kt = 0; kt < K_DIM / BK; ++kt) {
        __syncthreads();
        const int k0 = kt * BK;
#pragma unroll
        for (int r = 0; r < 4; ++r) {
            const int c    = r * 256 + t;
            const int row  = c >> 3;
            const int colg = (c & 7) ^ (row & 7);
            const size_t offA = (size_t)(bm * BM + row) * K_DIM + k0 + colg * 16;
            const size_t offB = (size_t)(bn * BN + row) * K_DIM + k0 + colg * 16;
            if (a8) async_copy16((const int8_t*)aptr + offA, &Als[c]);
            else    Als[c] = pack16((const int*)aptr + offA);
            if (b8) async_copy16((const int8_t*)bptr + offB, &Bls[c]);
            else    Bls[c] = pack16((const int*)bptr + offB);
        }
        __syncthreads();

#pragma unroll
        for (int s = 0; s < 2; ++s) {
            const int colk = s * 4 + qh;
            int32x4 af[4], bf[4];
#pragma unroll
            for (int i = 0; i < 4; ++i) {
                const int ra = wm + i * 16 + qm;
                const int rb = wn + i * 16 + qm;
                af[i] = Als[ra * 8 + (colk ^ (ra & 7))];
                bf[i] = Bls[rb * 8 + (colk ^ (rb & 7))];
            }
#pragma unroll
            for (int i = 0; i < 4; ++i)
#pragma unroll
                for (int j = 0; j < 4; ++j)
                    acc[i][j] = __builtin_amdgcn_mfma_i32_16x16x64_i8(
                        af[i], bf[j], acc[i][j], 0, 0, 0);
        }
    }
    ql_epilogue(acc, ws, out, bm, bn, wm, wn, qm, qh);
}

extern "C" void kernel_launch(void* const* d_in, const int* in_sizes, int n_in,
                              void* d_out, int out_size, void* d_ws, size_t ws_size,
                              hipStream_t stream) {
    const void* qin    = d_in[0];
    const void* qwt    = d_in[1];
    const int* qbias   = (const int*)d_in[2];
    const float* wscal = (const float*)d_in[3];
    int* ws  = (int*)d_ws;
    int* out = (int*)d_out;

    hipLaunchKernelGGL(ql_detect_kernel, dim3(1), dim3(64), 0, stream,
                       (const int*)qin, (const int*)qwt, ws);

    const size_t need = 65536 + (size_t)M_DIM * K_DIM + (size_t)N_DIM * K_DIM;
    if (ws_size >= need) {
        int8_t* a8 = (int8_t*)d_ws + 65536;
        int8_t* w8 = a8 + (size_t)M_DIM * K_DIM;
        const long ndwA = (long)M_DIM * K_DIM / 4;   // output dwords
        const long ndwW = (long)N_DIM * K_DIM / 4;
        // 4 dwords per thread via grid-stride
        hipLaunchKernelGGL(ql_pack_kernel, dim3((unsigned)(ndwW / (256 * 4))), dim3(256),
                           0, stream, qwt, (int*)w8, ws, 1, ndwW);
        hipLaunchKernelGGL(ql_pack_kernel, dim3((unsigned)(ndwA / (256 * 4))), dim3(256),
                           0, stream, qin, (int*)a8, ws, 0, ndwA);
        hipLaunchKernelGGL(ql_prep8_kernel, dim3(N_DIM / 4), dim3(256), 0, stream,
                           w8, qbias, wscal, ws);
        hipLaunchKernelGGL(ql_gemm_kernel, dim3(N_DIM / BN, M_DIM / BM), dim3(256), 0, stream,
                           a8, w8, ws, out);
    } else {
        hipLaunchKernelGGL(ql_prep_kernel, dim3(N_DIM / 4), dim3(256), 0, stream,
                           qwt, qbias, wscal, ws);
        hipLaunchKernelGGL(ql_gemm_fb_kernel, dim3(N_DIM / BN, M_DIM / BM), dim3(256), 0, stream,
                           qin, qwt, ws, out);
    }
}